// Round 1
// baseline (672.840 us; speedup 1.0000x reference)
//
#include <hip/hip_runtime.h>
#include <stdint.h>

#define N_PIX (512*512)
#define KW 512
#define KC 2048
#define NUM_CLS 68
#define WORD_THR 0.5f
#define CHAR_THR 0.25f
#define IOU_THR 0.3f

struct SelState {
  unsigned long long prefix;
  unsigned int kRem;
  unsigned int counter;
  unsigned int hist[256];
};

__device__ __forceinline__ unsigned long long word_key(const float* wfg, int i){
  float wf = wfg[i];
  float s = wf > WORD_THR ? wf : 0.0f;
  return (((unsigned long long)__float_as_uint(s)) << 32) | (unsigned long long)(0xFFFFFFFFu - (unsigned)i);
}
__device__ __forceinline__ unsigned long long char_key(const float* wfg, const float* cfg, int i){
  float wf = wfg[i]; float cf = cfg[i];
  float s = (wf > WORD_THR && cf > CHAR_THR) ? cf : 0.0f;
  return (((unsigned long long)__float_as_uint(s)) << 32) | (unsigned long long)(0xFFFFFFFFu - (unsigned)i);
}

__global__ void init_state(SelState* stW, SelState* stC){
  int t = threadIdx.x;
  if (t==0){ stW->prefix=0ull; stW->kRem=KW; stW->counter=0u; }
  if (t==1){ stC->prefix=0ull; stC->kRem=KC; stC->counter=0u; }
  for (int b=t; b<256; b+=blockDim.x){ stW->hist[b]=0u; stC->hist[b]=0u; }
}

__global__ void hist_pass(const float* __restrict__ wfg, const float* __restrict__ cfg,
                          SelState* stW, SelState* stC, int shift){
  __shared__ unsigned int hW[256], hC[256];
  for (int b=threadIdx.x;b<256;b+=blockDim.x){ hW[b]=0u; hC[b]=0u; }
  __syncthreads();
  unsigned long long maskHi = (shift>=56) ? 0ull : (~0ull << (shift+8));
  unsigned long long prefW = stW->prefix, prefC = stC->prefix;
  for (int i = blockIdx.x*blockDim.x+threadIdx.x; i < N_PIX; i += gridDim.x*blockDim.x){
    unsigned long long kWd = word_key(wfg,i);
    if ((kWd & maskHi)==prefW) atomicAdd(&hW[(unsigned)(kWd>>shift)&0xFFu],1u);
    unsigned long long kCh = char_key(wfg,cfg,i);
    if ((kCh & maskHi)==prefC) atomicAdd(&hC[(unsigned)(kCh>>shift)&0xFFu],1u);
  }
  __syncthreads();
  for (int b=threadIdx.x;b<256;b+=blockDim.x){
    if (hW[b]) atomicAdd(&stW->hist[b],hW[b]);
    if (hC[b]) atomicAdd(&stC->hist[b],hC[b]);
  }
}

__device__ void scan_one(SelState* st, int shift){
  unsigned int k = st->kRem;
  unsigned int cum = 0; int d = 255;
  while (d > 0 && cum + st->hist[d] < k){ cum += st->hist[d]; d--; }
  st->prefix |= ((unsigned long long)(unsigned)d) << shift;
  st->kRem = k - cum;
  for (int b=0;b<256;b++) st->hist[b]=0u;
}
__global__ void scan_pass(SelState* stW, SelState* stC, int shift){
  if (threadIdx.x==0) scan_one(stW, shift);
  else if (threadIdx.x==1) scan_one(stC, shift);
}

__global__ void compact_pass(const float* __restrict__ wfg, const float* __restrict__ cfg,
                             SelState* stW, SelState* stC,
                             unsigned long long* candW, unsigned long long* candC){
  unsigned long long tW = stW->prefix, tC = stC->prefix;
  for (int i = blockIdx.x*blockDim.x+threadIdx.x; i < N_PIX; i += gridDim.x*blockDim.x){
    unsigned long long kWd = word_key(wfg,i);
    if (kWd >= tW){ unsigned p = atomicAdd(&stW->counter,1u); if (p < KW) candW[p]=kWd; }
    unsigned long long kCh = char_key(wfg,cfg,i);
    if (kCh >= tC){ unsigned p = atomicAdd(&stC->counter,1u); if (p < KC) candC[p]=kCh; }
  }
}

template<int NS>
__global__ void bitonic_desc(unsigned long long* data){
  __shared__ unsigned long long s[NS];
  for (int t=threadIdx.x;t<NS;t+=blockDim.x) s[t]=data[t];
  __syncthreads();
  for (int k=2;k<=NS;k<<=1){
    for (int j=k>>1;j>0;j>>=1){
      for (int t=threadIdx.x;t<NS;t+=blockDim.x){
        int ixj = t ^ j;
        if (ixj > t){
          unsigned long long a=s[t], b=s[ixj];
          bool desc = ((t & k) == 0);
          if (desc ? (a < b) : (a > b)){ s[t]=b; s[ixj]=a; }
        }
      }
      __syncthreads();
    }
  }
  for (int t=threadIdx.x;t<NS;t+=blockDim.x) data[t]=s[t];
}

template<int STRIDE, bool USE_ORIENT, int KK>
__global__ void boxes_pass(const unsigned long long* __restrict__ cand,
                           const float* __restrict__ tblr, const float* __restrict__ orient,
                           const int* p_sw, const int* p_sh, const int* p_ow, const int* p_oh,
                           float* __restrict__ aabb, float* __restrict__ out_bbox){
  int k = blockIdx.x*blockDim.x + threadIdx.x;
  if (k >= KK) return;
  unsigned long long key = cand[k];
  unsigned idx = 0xFFFFFFFFu - (unsigned)(key & 0xFFFFFFFFull);
  float score = __uint_as_float((unsigned)(key>>32));
  float sw = (float)(*p_sw) * (float)STRIDE;
  float sh = (float)(*p_sh) * (float)STRIDE;
  float xf = (float)(idx & 511u), yf = (float)(idx >> 9);
  float t = tblr[0*N_PIX+idx], b = tblr[1*N_PIX+idx], l = tblr[2*N_PIX+idx], r = tblr[3*N_PIX+idx];
  float c = 1.0f, s = 0.0f;
  if (USE_ORIENT){ float o = orient[idx]; c = cosf(o); s = sinf(o); }
  float x1 = sw*(xf - l), x2 = sw*(xf + r);
  float y1 = sh*(yf - t), y2 = sh*(yf + b);
  float ax = sw*xf, ay = sh*yf;
  float cx[4] = {x1,x2,x2,x1};
  float cy[4] = {y1,y1,y2,y2};
  float rx[4], ry[4];
  #pragma unroll
  for (int q=0;q<4;q++){
    float dx = cx[q]-ax, dy = cy[q]-ay;
    rx[q] = ax + dx*c - dy*s;
    ry[q] = ay + dx*s + dy*c;
  }
  float minx = fminf(fminf(rx[0],rx[1]),fminf(rx[2],rx[3]));
  float maxx = fmaxf(fmaxf(rx[0],rx[1]),fmaxf(rx[2],rx[3]));
  float miny = fminf(fminf(ry[0],ry[1]),fminf(ry[2],ry[3]));
  float maxy = fmaxf(fmaxf(ry[0],ry[1]),fmaxf(ry[2],ry[3]));
  float area = fmaxf(maxx-minx,0.0f)*fmaxf(maxy-miny,0.0f);
  aabb[k*5+0]=minx; aabb[k*5+1]=miny; aabb[k*5+2]=maxx; aabb[k*5+3]=maxy; aabb[k*5+4]=area;
  float owm = (float)(*p_ow) - 1.0f, ohm = (float)(*p_oh) - 1.0f;
  #pragma unroll
  for (int q=0;q<4;q++){
    out_bbox[k*9 + 2*q]   = fminf(fmaxf(rintf(rx[q]),0.0f), owm);
    out_bbox[k*9 + 2*q+1] = fminf(fmaxf(rintf(ry[q]),0.0f), ohm);
  }
  out_bbox[k*9+8] = score;
}

template<int KK>
__global__ void sup_pass(const float* __restrict__ aabb, unsigned long long* __restrict__ sup){
  int i = blockIdx.x;
  int lane = threadIdx.x;
  float x1i=aabb[i*5], y1i=aabb[i*5+1], x2i=aabb[i*5+2], y2i=aabb[i*5+3], ai=aabb[i*5+4];
  const int W = KK/64;
  for (int w=0; w<W; w++){
    int j = w*64 + lane;
    float x1j=aabb[j*5], y1j=aabb[j*5+1], x2j=aabb[j*5+2], y2j=aabb[j*5+3], aj=aabb[j*5+4];
    float ix1=fmaxf(x1i,x1j), iy1=fmaxf(y1i,y1j);
    float ix2=fminf(x2i,x2j), iy2=fminf(y2i,y2j);
    float inter = fmaxf(ix2-ix1,0.0f)*fmaxf(iy2-iy1,0.0f);
    float iou = inter/(ai+aj-inter+1e-6f);
    bool bit = (iou > IOU_THR) && (j > i);
    unsigned long long m = __ballot(bit);
    if (lane==0) sup[(size_t)i*W + w] = m;
  }
}

template<int KK>
__global__ void fold_pass(const unsigned long long* __restrict__ sup,
                          const unsigned long long* __restrict__ cand,
                          float* __restrict__ keep_out){
  const int W = KK/64;
  int lane = threadIdx.x;
  unsigned long long keepw = ~0ull;
  unsigned long long r0=0ull,r1=0ull,r2=0ull,r3=0ull;
  if (lane < W){
    r0 = sup[0*W+lane]; r1 = sup[1*W+lane]; r2 = sup[2*W+lane]; r3 = sup[3*W+lane];
  }
  for (int i=0;i<KK;i+=4){
    {
      unsigned long long kw = __shfl(keepw, i>>6, 64);
      if ((kw >> (i&63)) & 1ull) keepw &= ~r0;
      if (lane < W && i+4 < KK) r0 = sup[(size_t)(i+4)*W+lane];
    }
    {
      int ii=i+1;
      unsigned long long kw = __shfl(keepw, ii>>6, 64);
      if ((kw >> (ii&63)) & 1ull) keepw &= ~r1;
      if (lane < W && i+5 < KK) r1 = sup[(size_t)(i+5)*W+lane];
    }
    {
      int ii=i+2;
      unsigned long long kw = __shfl(keepw, ii>>6, 64);
      if ((kw >> (ii&63)) & 1ull) keepw &= ~r2;
      if (lane < W && i+6 < KK) r2 = sup[(size_t)(i+6)*W+lane];
    }
    {
      int ii=i+3;
      unsigned long long kw = __shfl(keepw, ii>>6, 64);
      if ((kw >> (ii&63)) & 1ull) keepw &= ~r3;
      if (lane < W && i+7 < KK) r3 = sup[(size_t)(i+7)*W+lane];
    }
  }
  if (lane < W){
    for (int b=0;b<64;b++){
      int j = lane*64 + b;
      unsigned long long key = cand[j];
      bool pos = ((unsigned)(key>>32)) != 0u;
      bool kp = (((keepw >> b) & 1ull) != 0ull) && pos;
      keep_out[j] = kp ? 1.0f : 0.0f;
    }
  }
}

__global__ void gather_cls(const unsigned long long* __restrict__ candC,
                           const float* __restrict__ cls, float* __restrict__ out){
  int t = blockIdx.x*blockDim.x + threadIdx.x;
  if (t >= KC*NUM_CLS) return;
  int k = t / NUM_CLS;
  int c = t - k*NUM_CLS;
  unsigned idx = 0xFFFFFFFFu - (unsigned)(candC[k] & 0xFFFFFFFFull);
  out[t] = cls[(size_t)c*N_PIX + idx];
}

extern "C" void kernel_launch(void* const* d_in, const int* in_sizes, int n_in,
                              void* d_out, int out_size, void* d_ws, size_t ws_size,
                              hipStream_t stream) {
  const float* wfg   = (const float*)d_in[0];
  const float* wtblr = (const float*)d_in[1];
  const float* worient = (const float*)d_in[2];
  const float* cfg   = (const float*)d_in[3];
  const float* ctblr = (const float*)d_in[4];
  const float* ccls  = (const float*)d_in[5];
  const int* p_sw = (const int*)d_in[6];
  const int* p_sh = (const int*)d_in[7];
  const int* p_ow = (const int*)d_in[8];
  const int* p_oh = (const int*)d_in[9];

  char* ws = (char*)d_ws;
  SelState* stW = (SelState*)(ws + 0);
  SelState* stC = (SelState*)(ws + 2048);
  unsigned long long* candW = (unsigned long long*)(ws + 4096);          // 512*8   = 4096
  unsigned long long* candC = (unsigned long long*)(ws + 8192);          // 2048*8  = 16384
  float* aabbW = (float*)(ws + 24576);                                   // 512*5*4 = 10240
  float* aabbC = (float*)(ws + 34816);                                   // 2048*5*4= 40960
  unsigned long long* supW = (unsigned long long*)(ws + 75776);          // 512*8*8 = 32768
  unsigned long long* supC = (unsigned long long*)(ws + 108544);         // 2048*32*8 = 524288

  float* out = (float*)d_out;
  float* out_char_bbox   = out;                         // 2048*9
  float* out_char_scores = out + KC*9;                  // 2048*68
  float* out_word_bbox   = out + KC*9 + KC*NUM_CLS;     // 512*9
  float* out_wkeep       = out_word_bbox + KW*9;        // 512
  float* out_ckeep       = out_wkeep + KW;              // 2048

  init_state<<<1, 64, 0, stream>>>(stW, stC);
  for (int r = 0; r < 8; r++){
    int shift = 56 - 8*r;
    hist_pass<<<512, 256, 0, stream>>>(wfg, cfg, stW, stC, shift);
    scan_pass<<<1, 64, 0, stream>>>(stW, stC, shift);
  }
  compact_pass<<<512, 256, 0, stream>>>(wfg, cfg, stW, stC, candW, candC);
  bitonic_desc<KW><<<1, 512, 0, stream>>>(candW);
  bitonic_desc<KC><<<1, 1024, 0, stream>>>(candC);

  boxes_pass<4, true,  KW><<<KW/64, 64, 0, stream>>>(candW, wtblr, worient, p_sw, p_sh, p_ow, p_oh, aabbW, out_word_bbox);
  boxes_pass<4, false, KC><<<KC/64, 64, 0, stream>>>(candC, ctblr, nullptr,  p_sw, p_sh, p_ow, p_oh, aabbC, out_char_bbox);

  sup_pass<KW><<<KW, 64, 0, stream>>>(aabbW, supW);
  sup_pass<KC><<<KC, 64, 0, stream>>>(aabbC, supC);

  fold_pass<KW><<<1, 64, 0, stream>>>(supW, candW, out_wkeep);
  fold_pass<KC><<<1, 64, 0, stream>>>(supC, candC, out_ckeep);

  gather_cls<<<(KC*NUM_CLS + 255)/256, 256, 0, stream>>>(candC, ccls, out_char_scores);
}

// Round 2
// 451.455 us; speedup vs baseline: 1.4904x; 1.4904x over previous
//
#include <hip/hip_runtime.h>
#include <stdint.h>

typedef unsigned long long u64;
typedef unsigned int u32;

#define N_PIX (512*512)
#define KW 512
#define KC 2048
#define NUM_CLS 68
#define WORD_THR 0.5f
#define CHAR_THR 0.25f
#define IOU_THR 0.3f

struct SelState {
  u64 prefix;
  u32 kRem;
  u32 counter;
  u32 done;
  u32 pad;
  u32 hist[256];
};

__device__ __forceinline__ u64 word_key(const float* wfg, int i){
  float wf = wfg[i];
  float s = wf > WORD_THR ? wf : 0.0f;
  return (((u64)__float_as_uint(s)) << 32) | (u64)(0xFFFFFFFFu - (u32)i);
}
__device__ __forceinline__ u64 char_key(const float* wfg, const float* cfg, int i){
  float wf = wfg[i]; float cf = cfg[i];
  float s = (wf > WORD_THR && cf > CHAR_THR) ? cf : 0.0f;
  return (((u64)__float_as_uint(s)) << 32) | (u64)(0xFFFFFFFFu - (u32)i);
}

__global__ void init_state(SelState* stW, SelState* stC){
  int t = threadIdx.x;
  if (t==0){ stW->prefix=0ull; stW->kRem=KW; stW->counter=0u; stW->done=0u; }
  if (t==1){ stC->prefix=0ull; stC->kRem=KC; stC->counter=0u; stC->done=0u; }
  for (int b=t; b<256; b+=64){ stW->hist[b]=0u; stC->hist[b]=0u; }
}

// hist + (last block) parallel scan fused via done-counter
__global__ void hist_scan(const float* __restrict__ wfg, const float* __restrict__ cfg,
                          SelState* stW, SelState* stC, int shift){
  __shared__ u32 hW[256], hC[256];
  __shared__ int isLast;
  int tid = threadIdx.x;
  for (int b=tid;b<256;b+=256){ hW[b]=0u; hC[b]=0u; }
  __syncthreads();
  u64 maskHi = (shift>=56) ? 0ull : (~0ull << (shift+8));
  u64 prefW = stW->prefix, prefC = stC->prefix;
  for (int i = blockIdx.x*256+tid; i < N_PIX; i += gridDim.x*256){
    u64 kWd = word_key(wfg,i);
    if ((kWd & maskHi)==prefW) atomicAdd(&hW[(u32)(kWd>>shift)&255u],1u);
    u64 kCh = char_key(wfg,cfg,i);
    if ((kCh & maskHi)==prefC) atomicAdd(&hC[(u32)(kCh>>shift)&255u],1u);
  }
  __syncthreads();
  for (int b=tid;b<256;b+=256){
    if (hW[b]) atomicAdd(&stW->hist[b],hW[b]);
    if (hC[b]) atomicAdd(&stC->hist[b],hC[b]);
  }
  __threadfence();
  __syncthreads();
  if (tid==0){ u32 p = atomicAdd(&stW->done,1u); isLast = (p == gridDim.x-1); }
  __syncthreads();
  if (!isLast) return;
  if (tid==0) stW->done = 0u;
  // parallel scan: wave 0 -> word, wave 1 -> char
  int wv = tid>>6, lane = tid&63;
  if (wv < 2){
    SelState* st = (wv==0) ? stW : stC;
    u32 h[4];
    #pragma unroll
    for (int q=0;q<4;q++) h[q] = atomicAdd(&st->hist[lane*4+q], 0u); // coherent read
    u32 lsum = h[0]+h[1]+h[2]+h[3];
    // inclusive suffix-sum over lanes
    u32 v = lsum;
    #pragma unroll
    for (int off=1; off<64; off<<=1){
      u32 t2 = __shfl_down(v, off, 64);
      if (lane + off < 64) v += t2;
    }
    u32 above = v - lsum;                 // sum over lanes > lane
    u32 k = st->kRem;
    u32 sfx1 = h[3]+h[2]+h[1];            // suffix within lane
    u32 sfx2 = h[3]+h[2];
    u32 sfx3 = h[3];
    // F(d) = count of keys with digit >= d (within current prefix class)
    int best = -1;
    if (above + sfx3          >= k) best = lane*4+3;
    else if (above + sfx2     >= k) best = lane*4+2;
    else if (above + sfx1     >= k) best = lane*4+1;
    else if (above + lsum     >= k) best = lane*4+0;
    u64 m = __ballot(best >= 0);          // nonzero: F(0)=total >= k invariant
    int hi_lane = 63 - __clzll(m);
    int d = __shfl(best, hi_lane, 64);
    u32 fd1_local = 0;
    if (lane == hi_lane){
      int q = d & 3;
      fd1_local = above + (q==3 ? 0u : (q==2 ? sfx3 : (q==1 ? sfx2 : sfx1)));
    }
    u32 fd1 = __shfl(fd1_local, hi_lane, 64);
    if (lane==0){
      st->prefix |= ((u64)(u32)d) << shift;
      st->kRem = k - fd1;
    }
    #pragma unroll
    for (int q=0;q<4;q++) st->hist[lane*4+q] = 0u; // zero for next round
  }
}

template<int NS>
__device__ void sort_desc(u64* data, u64* s){
  for (int t=threadIdx.x;t<NS;t+=1024) s[t]=data[t];
  __syncthreads();
  for (int k=2;k<=NS;k<<=1){
    for (int j=k>>1;j>0;j>>=1){
      for (int t=threadIdx.x;t<NS;t+=1024){
        int ixj = t ^ j;
        if (ixj > t){
          u64 a=s[t], b=s[ixj];
          bool desc = ((t & k) == 0);
          if (desc ? (a < b) : (a > b)){ s[t]=b; s[ixj]=a; }
        }
      }
      __syncthreads();
    }
  }
  for (int t=threadIdx.x;t<NS;t+=1024) data[t]=s[t];
  __syncthreads();
}

__global__ __launch_bounds__(1024)
void compact_sort(const float* __restrict__ wfg, const float* __restrict__ cfg,
                  SelState* stW, SelState* stC, u64* candW, u64* candC){
  __shared__ u64 s[KC];  // 16 KB, reused for both sorts
  __shared__ int isLast;
  int tid = threadIdx.x;
  int i = blockIdx.x*1024 + tid;          // grid 256 -> exactly N_PIX
  u64 tW = stW->prefix, tC = stC->prefix;
  u64 kWd = word_key(wfg,i);
  if (kWd >= tW){ u32 p = atomicAdd(&stW->counter,1u); if (p < KW) candW[p]=kWd; }
  u64 kCh = char_key(wfg,cfg,i);
  if (kCh >= tC){ u32 p = atomicAdd(&stC->counter,1u); if (p < KC) candC[p]=kCh; }
  __threadfence();
  __syncthreads();
  if (tid==0){ u32 p = atomicAdd(&stW->done,1u); isLast = (p == gridDim.x-1); }
  __syncthreads();
  if (!isLast) return;
  if (tid==0) stW->done = 0u;
  sort_desc<KW>(candW, s);
  sort_desc<KC>(candC, s);
}

template<bool USE_ORIENT, int KK>
__device__ void boxes_body(int k, const u64* __restrict__ cand,
                           const float* __restrict__ tblr, const float* __restrict__ orient,
                           float sw, float sh, float owm, float ohm,
                           float* __restrict__ aabb, float* __restrict__ out_bbox){
  u64 key = cand[k];
  u32 idx = 0xFFFFFFFFu - (u32)(key & 0xFFFFFFFFull);
  float score = __uint_as_float((u32)(key>>32));
  float xf = (float)(idx & 511u), yf = (float)(idx >> 9);
  float t = tblr[0*N_PIX+idx], b = tblr[1*N_PIX+idx], l = tblr[2*N_PIX+idx], r = tblr[3*N_PIX+idx];
  float c = 1.0f, sn = 0.0f;
  if (USE_ORIENT){ float o = orient[idx]; c = cosf(o); sn = sinf(o); }
  float x1 = sw*(xf - l), x2 = sw*(xf + r);
  float y1 = sh*(yf - t), y2 = sh*(yf + b);
  float ax = sw*xf, ay = sh*yf;
  float cx[4] = {x1,x2,x2,x1};
  float cy[4] = {y1,y1,y2,y2};
  float rx[4], ry[4];
  #pragma unroll
  for (int q=0;q<4;q++){
    float dx = cx[q]-ax, dy = cy[q]-ay;
    rx[q] = ax + dx*c - dy*sn;
    ry[q] = ay + dx*sn + dy*c;
  }
  float minx = fminf(fminf(rx[0],rx[1]),fminf(rx[2],rx[3]));
  float maxx = fmaxf(fmaxf(rx[0],rx[1]),fmaxf(rx[2],rx[3]));
  float miny = fminf(fminf(ry[0],ry[1]),fminf(ry[2],ry[3]));
  float maxy = fmaxf(fmaxf(ry[0],ry[1]),fmaxf(ry[2],ry[3]));
  float area = fmaxf(maxx-minx,0.0f)*fmaxf(maxy-miny,0.0f);
  aabb[k*5+0]=minx; aabb[k*5+1]=miny; aabb[k*5+2]=maxx; aabb[k*5+3]=maxy; aabb[k*5+4]=area;
  #pragma unroll
  for (int q=0;q<4;q++){
    out_bbox[k*9 + 2*q]   = fminf(fmaxf(rintf(rx[q]),0.0f), owm);
    out_bbox[k*9 + 2*q+1] = fminf(fmaxf(rintf(ry[q]),0.0f), ohm);
  }
  out_bbox[k*9+8] = score;
}

__global__ void boxes_fused(const u64* __restrict__ candW, const u64* __restrict__ candC,
                            const float* __restrict__ wtblr, const float* __restrict__ worient,
                            const float* __restrict__ ctblr,
                            const int* p_sw, const int* p_sh, const int* p_ow, const int* p_oh,
                            float* aabbW, float* aabbC, float* outW, float* outC){
  int b = blockIdx.x, tid = threadIdx.x;
  float sw = (float)(*p_sw) * 4.0f;   // WORD_STRIDE == CHAR_STRIDE == 4
  float sh = (float)(*p_sh) * 4.0f;
  float owm = (float)(*p_ow) - 1.0f, ohm = (float)(*p_oh) - 1.0f;
  if (b < KW/64)
    boxes_body<true, KW>(b*64+tid, candW, wtblr, worient, sw, sh, owm, ohm, aabbW, outW);
  else
    boxes_body<false, KC>((b-KW/64)*64+tid, candC, ctblr, nullptr, sw, sh, owm, ohm, aabbC, outC);
}

// TRANSPOSED suppression: supT[j][w] bit b  <=>  box i=w*64+b suppresses j (i<j, IoU>thr)
template<int W>
__device__ void sup_body(int j, const float* __restrict__ aabb, u64* __restrict__ supT){
  int lane = threadIdx.x;
  float x1j=aabb[j*5], y1j=aabb[j*5+1], x2j=aabb[j*5+2], y2j=aabb[j*5+3], aj=aabb[j*5+4];
  #pragma unroll 4
  for (int w=0; w<W; w++){
    int i = w*64 + lane;
    float x1i=aabb[i*5], y1i=aabb[i*5+1], x2i=aabb[i*5+2], y2i=aabb[i*5+3], ai=aabb[i*5+4];
    float ix1=fmaxf(x1i,x1j), iy1=fmaxf(y1i,y1j);
    float ix2=fminf(x2i,x2j), iy2=fminf(y2i,y2j);
    float inter = fmaxf(ix2-ix1,0.0f)*fmaxf(iy2-iy1,0.0f);
    float iou = inter/(ai+aj-inter+1e-6f);
    bool bit = (iou > IOU_THR) && (i < j);
    u64 m = __ballot(bit);
    if (lane==0) supT[(size_t)j*W + w] = m;
  }
}

__global__ void sup_fused(const float* __restrict__ aabbW, const float* __restrict__ aabbC,
                          u64* supTW, u64* supTC){
  int b = blockIdx.x;
  if (b < KW) sup_body<KW/64>(b, aabbW, supTW);
  else        sup_body<KC/64>(b-KW, aabbC, supTC);
}

// Jacobi fixpoint of keep[j] = !exists i<j: keep[i] & sup[i][j]
// (unique fixed point == greedy NMS result; converges in <= maxdepth+1 iters)
template<int K, int W>
__device__ void nms_fix_body(const u64* __restrict__ supT, const u64* __restrict__ cand,
                             float* __restrict__ keep_out, u64* kw, int* changed){
  int tid = threadIdx.x;
  int lane = tid & 63;
  int wv = tid >> 6;
  constexpr int NB = (K + 1023)/1024;
  if (tid < W) kw[tid] = ~0ull;
  __syncthreads();
  for (;;){
    if (tid==0) *changed = 0;
    __syncthreads();
    bool nb0=false, nb1=false;
    {
      int j = tid;
      if (j < K){
        u64 su = 0ull;
        const u64* row = supT + (size_t)j*W;
        #pragma unroll
        for (int w=0; w<W; w++) su |= row[w] & kw[w];
        nb0 = (su == 0ull);
      }
      if (NB > 1){
        int j2 = tid + 1024;
        u64 su = 0ull;
        const u64* row = supT + (size_t)j2*W;
        #pragma unroll
        for (int w=0; w<W; w++) su |= row[w] & kw[w];
        nb1 = (su == 0ull);
      }
    }
    __syncthreads();   // all reads of kw done
    if (wv < K/64){
      u64 b = __ballot(nb0);
      if (lane==0){ if (b != kw[wv]){ kw[wv] = b; *changed = 1; } }
    }
    if (NB > 1){
      u64 b = __ballot(nb1);
      if (lane==0){ int widx = 16 + wv; if (b != kw[widx]){ kw[widx] = b; *changed = 1; } }
    }
    __syncthreads();   // writes visible
    int ch = *changed;
    __syncthreads();   // reads done before next reset
    if (!ch) break;
  }
  #pragma unroll
  for (int q=0; q<NB; q++){
    int j = tid + q*1024;
    if (j < K){
      u64 key = cand[j];
      bool pos = ((u32)(key>>32)) != 0u;
      bool kp = (((kw[j>>6] >> (j&63)) & 1ull) != 0ull) && pos;
      keep_out[j] = kp ? 1.0f : 0.0f;
    }
  }
}

__global__ __launch_bounds__(1024)
void nms_fixpoint(const u64* supTW, const u64* candW, float* keepW,
                  const u64* supTC, const u64* candC, float* keepC){
  __shared__ u64 kw[KC/64];
  __shared__ int changed;
  if (blockIdx.x == 0) nms_fix_body<KW, KW/64>(supTW, candW, keepW, kw, &changed);
  else                 nms_fix_body<KC, KC/64>(supTC, candC, keepC, kw, &changed);
}

__global__ void gather_cls(const u64* __restrict__ candC,
                           const float* __restrict__ cls, float* __restrict__ out){
  int t = blockIdx.x*blockDim.x + threadIdx.x;
  if (t >= KC*NUM_CLS) return;
  int k = t / NUM_CLS;
  int c = t - k*NUM_CLS;
  u32 idx = 0xFFFFFFFFu - (u32)(candC[k] & 0xFFFFFFFFull);
  out[t] = cls[(size_t)c*N_PIX + idx];
}

extern "C" void kernel_launch(void* const* d_in, const int* in_sizes, int n_in,
                              void* d_out, int out_size, void* d_ws, size_t ws_size,
                              hipStream_t stream) {
  const float* wfg     = (const float*)d_in[0];
  const float* wtblr   = (const float*)d_in[1];
  const float* worient = (const float*)d_in[2];
  const float* cfg     = (const float*)d_in[3];
  const float* ctblr   = (const float*)d_in[4];
  const float* ccls    = (const float*)d_in[5];
  const int* p_sw = (const int*)d_in[6];
  const int* p_sh = (const int*)d_in[7];
  const int* p_ow = (const int*)d_in[8];
  const int* p_oh = (const int*)d_in[9];

  char* ws = (char*)d_ws;
  SelState* stW = (SelState*)(ws + 0);
  SelState* stC = (SelState*)(ws + 2048);
  u64* candW = (u64*)(ws + 4096);            // 512*8   = 4096
  u64* candC = (u64*)(ws + 8192);            // 2048*8  = 16384
  float* aabbW = (float*)(ws + 24576);       // 512*5*4 = 10240
  float* aabbC = (float*)(ws + 34816);       // 2048*5*4= 40960
  u64* supTW = (u64*)(ws + 75776);           // 512*8*8 = 32768
  u64* supTC = (u64*)(ws + 108544);          // 2048*32*8 = 524288

  float* out = (float*)d_out;
  float* out_char_bbox   = out;                         // 2048*9
  float* out_char_scores = out + KC*9;                  // 2048*68
  float* out_word_bbox   = out + KC*9 + KC*NUM_CLS;     // 512*9
  float* out_wkeep       = out_word_bbox + KW*9;        // 512
  float* out_ckeep       = out_wkeep + KW;              // 2048

  init_state<<<1, 64, 0, stream>>>(stW, stC);
  for (int r = 0; r < 8; r++){
    int shift = 56 - 8*r;
    hist_scan<<<512, 256, 0, stream>>>(wfg, cfg, stW, stC, shift);
  }
  compact_sort<<<256, 1024, 0, stream>>>(wfg, cfg, stW, stC, candW, candC);
  boxes_fused<<<(KW+KC)/64, 64, 0, stream>>>(candW, candC, wtblr, worient, ctblr,
                                             p_sw, p_sh, p_ow, p_oh,
                                             aabbW, aabbC, out_word_bbox, out_char_bbox);
  sup_fused<<<KW+KC, 64, 0, stream>>>(aabbW, aabbC, supTW, supTC);
  nms_fixpoint<<<2, 1024, 0, stream>>>(supTW, candW, out_wkeep, supTC, candC, out_ckeep);
  gather_cls<<<(KC*NUM_CLS + 255)/256, 256, 0, stream>>>(candC, ccls, out_char_scores);
}

// Round 3
// 232.979 us; speedup vs baseline: 2.8880x; 1.9377x over previous
//
#include <hip/hip_runtime.h>
#include <stdint.h>

typedef unsigned long long u64;
typedef unsigned int u32;

#define N_PIX (512*512)
#define KW 512
#define KC 2048
#define CAPW 4096
#define CAPC 4096
#define NUM_CLS 68
#define WORD_THR 0.5f
#define CHAR_THR 0.25f
#define IOU_THR 0.3f

struct SelState {
  u64 prefix;
  u32 kRem;
  u32 counter;
  u32 done;
  u32 pad;
  u32 hist[256];
};

__device__ __forceinline__ u64 word_key(const float* wfg, int i){
  float wf = wfg[i];
  float s = wf > WORD_THR ? wf : 0.0f;
  return (((u64)__float_as_uint(s)) << 32) | (u64)(0xFFFFFFFFu - (u32)i);
}
__device__ __forceinline__ u64 char_key(const float* wfg, const float* cfg, int i){
  float wf = wfg[i]; float cf = cfg[i];
  float s = (wf > WORD_THR && cf > CHAR_THR) ? cf : 0.0f;
  return (((u64)__float_as_uint(s)) << 32) | (u64)(0xFFFFFFFFu - (u32)i);
}

__global__ void init_state(SelState* stW, SelState* stC){
  int t = threadIdx.x;
  if (t==0){ stW->prefix=0ull; stW->kRem=KW; stW->counter=0u; stW->done=0u; }
  if (t==1){ stC->prefix=0ull; stC->kRem=KC; stC->counter=0u; stC->done=0u; }
  for (int b=t; b<256; b+=64){ stW->hist[b]=0u; stC->hist[b]=0u; }
}

// hist + (last block) parallel scan fused via done-counter
__global__ void hist_scan(const float* __restrict__ wfg, const float* __restrict__ cfg,
                          SelState* stW, SelState* stC, int shift){
  __shared__ u32 hW[256], hC[256];
  __shared__ int isLast;
  int tid = threadIdx.x;
  for (int b=tid;b<256;b+=256){ hW[b]=0u; hC[b]=0u; }
  __syncthreads();
  u64 maskHi = (shift>=56) ? 0ull : (~0ull << (shift+8));
  u64 prefW = stW->prefix, prefC = stC->prefix;
  for (int i = blockIdx.x*256+tid; i < N_PIX; i += gridDim.x*256){
    u64 kWd = word_key(wfg,i);
    if ((kWd & maskHi)==prefW) atomicAdd(&hW[(u32)(kWd>>shift)&255u],1u);
    u64 kCh = char_key(wfg,cfg,i);
    if ((kCh & maskHi)==prefC) atomicAdd(&hC[(u32)(kCh>>shift)&255u],1u);
  }
  __syncthreads();
  for (int b=tid;b<256;b+=256){
    if (hW[b]) atomicAdd(&stW->hist[b],hW[b]);
    if (hC[b]) atomicAdd(&stC->hist[b],hC[b]);
  }
  __threadfence();
  __syncthreads();
  if (tid==0){ u32 p = atomicAdd(&stW->done,1u); isLast = (p == gridDim.x-1); }
  __syncthreads();
  if (!isLast) return;
  if (tid==0) stW->done = 0u;
  // parallel scan: wave 0 -> word, wave 1 -> char
  int wv = tid>>6, lane = tid&63;
  if (wv < 2){
    SelState* st = (wv==0) ? stW : stC;
    u32 h[4];
    #pragma unroll
    for (int q=0;q<4;q++) h[q] = atomicAdd(&st->hist[lane*4+q], 0u); // coherent read
    u32 lsum = h[0]+h[1]+h[2]+h[3];
    u32 v = lsum;
    #pragma unroll
    for (int off=1; off<64; off<<=1){
      u32 t2 = __shfl_down(v, off, 64);
      if (lane + off < 64) v += t2;
    }
    u32 above = v - lsum;                 // sum over lanes > lane
    u32 k = st->kRem;
    u32 sfx1 = h[3]+h[2]+h[1];
    u32 sfx2 = h[3]+h[2];
    u32 sfx3 = h[3];
    int best = -1;
    if (above + sfx3          >= k) best = lane*4+3;
    else if (above + sfx2     >= k) best = lane*4+2;
    else if (above + sfx1     >= k) best = lane*4+1;
    else if (above + lsum     >= k) best = lane*4+0;
    u64 m = __ballot(best >= 0);
    int hi_lane = 63 - __clzll(m);
    int d = __shfl(best, hi_lane, 64);
    u32 fd1_local = 0;
    if (lane == hi_lane){
      int q = d & 3;
      fd1_local = above + (q==3 ? 0u : (q==2 ? sfx3 : (q==1 ? sfx2 : sfx1)));
    }
    u32 fd1 = __shfl(fd1_local, hi_lane, 64);
    if (lane==0){
      st->prefix |= ((u64)(u32)d) << shift;
      st->kRem = k - fd1;
    }
    #pragma unroll
    for (int q=0;q<4;q++) st->hist[lane*4+q] = 0u;
  }
}

__global__ __launch_bounds__(1024)
void compact(const float* __restrict__ wfg, const float* __restrict__ cfg,
             SelState* stW, SelState* stC, u64* candW, u64* candC){
  int i = blockIdx.x*1024 + threadIdx.x;   // grid 256 -> exactly N_PIX
  u64 tW = stW->prefix, tC = stC->prefix;
  u64 kWd = word_key(wfg,i);
  if (kWd >= tW){ u32 p = atomicAdd(&stW->counter,1u); if (p < CAPW) candW[p]=kWd; }
  u64 kCh = char_key(wfg,cfg,i);
  if (kCh >= tC){ u32 p = atomicAdd(&stC->counter,1u); if (p < CAPC) candC[p]=kCh; }
}

// exact rank by enumeration (keys unique), fused with box construction
__global__ __launch_bounds__(256)
void rank_boxes(const u64* __restrict__ candW, const u64* __restrict__ candC,
                SelState* stW, SelState* stC,
                const float* __restrict__ wtblr, const float* __restrict__ worient,
                const float* __restrict__ ctblr,
                const int* p_sw, const int* p_sh, const int* p_ow, const int* p_oh,
                u64* sortedW, u64* sortedC, float* aabbW, float* aabbC,
                float* outW, float* outC){
  int t = blockIdx.x*256 + threadIdx.x;
  bool isW = (t < CAPW);                     // CAPW multiple of 256 -> block-uniform
  const u64* cand = isW ? candW : candC;
  SelState* st = isW ? stW : stC;
  int cap = isW ? CAPW : CAPC;
  int slot = isW ? t : (t - CAPW);
  int C = (int)st->counter; if (C > cap) C = cap;
  if (slot >= C) return;
  u64 my = cand[slot];
  int rank = 0;
  int C2 = C >> 1;
  const ulonglong2* c2p = (const ulonglong2*)cand;
  #pragma unroll 4
  for (int i=0;i<C2;i++){ ulonglong2 v = c2p[i]; rank += (v.x > my) + (v.y > my); }
  if (C & 1) rank += (cand[C-1] > my);
  int K = isW ? KW : KC;
  if (rank >= K) return;
  (isW ? sortedW : sortedC)[rank] = my;

  u32 idx = 0xFFFFFFFFu - (u32)(my & 0xFFFFFFFFull);
  float score = __uint_as_float((u32)(my>>32));
  float sw = (float)(*p_sw) * 4.0f;          // WORD_STRIDE == CHAR_STRIDE == 4
  float sh = (float)(*p_sh) * 4.0f;
  float owm = (float)(*p_ow) - 1.0f, ohm = (float)(*p_oh) - 1.0f;
  const float* tblr = isW ? wtblr : ctblr;
  float tt = tblr[idx], bb = tblr[N_PIX+idx], ll = tblr[2*N_PIX+idx], rr = tblr[3*N_PIX+idx];
  float xf = (float)(idx & 511u), yf = (float)(idx >> 9);
  float c = 1.0f, sn = 0.0f;
  if (isW){ float o = worient[idx]; c = cosf(o); sn = sinf(o); }
  float x1 = sw*(xf - ll), x2 = sw*(xf + rr);
  float y1 = sh*(yf - tt), y2 = sh*(yf + bb);
  float ax = sw*xf, ay = sh*yf;
  float cx[4] = {x1,x2,x2,x1};
  float cy[4] = {y1,y1,y2,y2};
  float rx[4], ry[4];
  #pragma unroll
  for (int q=0;q<4;q++){
    float dx = cx[q]-ax, dy = cy[q]-ay;
    rx[q] = ax + dx*c - dy*sn;
    ry[q] = ay + dx*sn + dy*c;
  }
  float minx = fminf(fminf(rx[0],rx[1]),fminf(rx[2],rx[3]));
  float maxx = fmaxf(fmaxf(rx[0],rx[1]),fmaxf(rx[2],rx[3]));
  float miny = fminf(fminf(ry[0],ry[1]),fminf(ry[2],ry[3]));
  float maxy = fmaxf(fmaxf(ry[0],ry[1]),fmaxf(ry[2],ry[3]));
  float area = fmaxf(maxx-minx,0.0f)*fmaxf(maxy-miny,0.0f);
  float* aabb = isW ? aabbW : aabbC;
  aabb[rank*5+0]=minx; aabb[rank*5+1]=miny; aabb[rank*5+2]=maxx; aabb[rank*5+3]=maxy; aabb[rank*5+4]=area;
  float* ob = isW ? outW : outC;
  #pragma unroll
  for (int q=0;q<4;q++){
    ob[rank*9 + 2*q]   = fminf(fmaxf(rintf(rx[q]),0.0f), owm);
    ob[rank*9 + 2*q+1] = fminf(fmaxf(rintf(ry[q]),0.0f), ohm);
  }
  ob[rank*9+8] = score;
}

// TRANSPOSED suppression: supT[j][w] bit b  <=>  box i=w*64+b suppresses j (i<j, IoU>thr)
template<int W>
__device__ void sup_body(int j, int lane, const float* __restrict__ aabb, u64* __restrict__ supT){
  float x1j=aabb[j*5], y1j=aabb[j*5+1], x2j=aabb[j*5+2], y2j=aabb[j*5+3], aj=aabb[j*5+4];
  #pragma unroll 4
  for (int w=0; w<W; w++){
    int i = w*64 + lane;
    float x1i=aabb[i*5], y1i=aabb[i*5+1], x2i=aabb[i*5+2], y2i=aabb[i*5+3], ai=aabb[i*5+4];
    float ix1=fmaxf(x1i,x1j), iy1=fmaxf(y1i,y1j);
    float ix2=fminf(x2i,x2j), iy2=fminf(y2i,y2j);
    float inter = fmaxf(ix2-ix1,0.0f)*fmaxf(iy2-iy1,0.0f);
    float iou = inter/(ai+aj-inter+1e-6f);
    bool bit = (iou > IOU_THR) && (i < j);
    u64 m = __ballot(bit);
    if (lane==0) supT[(size_t)j*W + w] = m;
  }
}

#define SUPB ((KW+KC)/4)          // 4 rows (one per wave) per 256-thread block
#define GATHB ((KC*NUM_CLS+255)/256)

__global__ __launch_bounds__(256)
void sup_gather(const float* __restrict__ aabbW, const float* __restrict__ aabbC,
                u64* supTW, u64* supTC,
                const u64* __restrict__ sortedC, const float* __restrict__ cls,
                float* __restrict__ out_cls){
  int b = blockIdx.x;
  if (b < SUPB){
    int wv = threadIdx.x >> 6, lane = threadIdx.x & 63;
    int row = b*4 + wv;
    if (row < KW) sup_body<KW/64>(row, lane, aabbW, supTW);
    else          sup_body<KC/64>(row - KW, lane, aabbC, supTC);
  } else {
    int t = (b - SUPB)*256 + threadIdx.x;
    if (t < KC*NUM_CLS){
      int k = t / NUM_CLS;
      int c = t - k*NUM_CLS;
      u32 idx = 0xFFFFFFFFu - (u32)(sortedC[k] & 0xFFFFFFFFull);
      out_cls[t] = cls[(size_t)c*N_PIX + idx];
    }
  }
}

// Jacobi fixpoint of keep[j] = !exists i<j: keep[i] & sup[i][j]
template<int K, int W>
__device__ void nms_fix_body(const u64* __restrict__ supT, const u64* __restrict__ cand,
                             float* __restrict__ keep_out, u64* kw, int* changed){
  int tid = threadIdx.x;
  int lane = tid & 63;
  int wv = tid >> 6;
  constexpr int NB = (K + 1023)/1024;
  if (tid < W) kw[tid] = ~0ull;
  __syncthreads();
  for (;;){
    if (tid==0) *changed = 0;
    __syncthreads();
    bool nb0=false, nb1=false;
    {
      int j = tid;
      if (j < K){
        u64 su = 0ull;
        const u64* row = supT + (size_t)j*W;
        #pragma unroll
        for (int w=0; w<W; w++) su |= row[w] & kw[w];
        nb0 = (su == 0ull);
      }
      if (NB > 1){
        int j2 = tid + 1024;
        u64 su = 0ull;
        const u64* row = supT + (size_t)j2*W;
        #pragma unroll
        for (int w=0; w<W; w++) su |= row[w] & kw[w];
        nb1 = (su == 0ull);
      }
    }
    __syncthreads();
    if (wv < K/64){
      u64 b = __ballot(nb0);
      if (lane==0){ if (b != kw[wv]){ kw[wv] = b; *changed = 1; } }
    }
    if (NB > 1){
      u64 b = __ballot(nb1);
      if (lane==0){ int widx = 16 + wv; if (b != kw[widx]){ kw[widx] = b; *changed = 1; } }
    }
    __syncthreads();
    int ch = *changed;
    __syncthreads();
    if (!ch) break;
  }
  #pragma unroll
  for (int q=0; q<NB; q++){
    int j = tid + q*1024;
    if (j < K){
      u64 key = cand[j];
      bool pos = ((u32)(key>>32)) != 0u;
      bool kp = (((kw[j>>6] >> (j&63)) & 1ull) != 0ull) && pos;
      keep_out[j] = kp ? 1.0f : 0.0f;
    }
  }
}

__global__ __launch_bounds__(1024)
void nms_fixpoint(const u64* supTW, const u64* sortedW, float* keepW,
                  const u64* supTC, const u64* sortedC, float* keepC){
  __shared__ u64 kw[KC/64];
  __shared__ int changed;
  if (blockIdx.x == 0) nms_fix_body<KW, KW/64>(supTW, sortedW, keepW, kw, &changed);
  else                 nms_fix_body<KC, KC/64>(supTC, sortedC, keepC, kw, &changed);
}

extern "C" void kernel_launch(void* const* d_in, const int* in_sizes, int n_in,
                              void* d_out, int out_size, void* d_ws, size_t ws_size,
                              hipStream_t stream) {
  const float* wfg     = (const float*)d_in[0];
  const float* wtblr   = (const float*)d_in[1];
  const float* worient = (const float*)d_in[2];
  const float* cfg     = (const float*)d_in[3];
  const float* ctblr   = (const float*)d_in[4];
  const float* ccls    = (const float*)d_in[5];
  const int* p_sw = (const int*)d_in[6];
  const int* p_sh = (const int*)d_in[7];
  const int* p_ow = (const int*)d_in[8];
  const int* p_oh = (const int*)d_in[9];

  // ws layout (overlays: cand* dead before supT* written; peak 632832 B)
  char* ws = (char*)d_ws;
  u64* candW   = (u64*)(ws + 0);        // CAPW*8 = 32768
  u64* candC   = (u64*)(ws + 32768);    // CAPC*8 = 32768
  u64* supTW   = (u64*)(ws + 0);        // 512*8*8  = 32768   (overlays candW)
  u64* supTC   = (u64*)(ws + 32768);    // 2048*32*8= 524288  (overlays candC+)
  u64* sortedW = (u64*)(ws + 557056);   // 512*8  = 4096
  u64* sortedC = (u64*)(ws + 561152);   // 2048*8 = 16384
  float* aabbW = (float*)(ws + 577536); // 512*5*4 = 10240
  float* aabbC = (float*)(ws + 587776); // 2048*5*4= 40960
  SelState* stW = (SelState*)(ws + 628736);
  SelState* stC = (SelState*)(ws + 630784); // end 632832

  float* out = (float*)d_out;
  float* out_char_bbox   = out;                         // 2048*9
  float* out_char_scores = out + KC*9;                  // 2048*68
  float* out_word_bbox   = out + KC*9 + KC*NUM_CLS;     // 512*9
  float* out_wkeep       = out_word_bbox + KW*9;        // 512
  float* out_ckeep       = out_wkeep + KW;              // 2048

  init_state<<<1, 64, 0, stream>>>(stW, stC);
  hist_scan<<<512, 256, 0, stream>>>(wfg, cfg, stW, stC, 56);
  hist_scan<<<512, 256, 0, stream>>>(wfg, cfg, stW, stC, 48);
  compact<<<256, 1024, 0, stream>>>(wfg, cfg, stW, stC, candW, candC);
  rank_boxes<<<(CAPW+CAPC)/256, 256, 0, stream>>>(candW, candC, stW, stC,
                                                  wtblr, worient, ctblr,
                                                  p_sw, p_sh, p_ow, p_oh,
                                                  sortedW, sortedC, aabbW, aabbC,
                                                  out_word_bbox, out_char_bbox);
  sup_gather<<<SUPB + GATHB, 256, 0, stream>>>(aabbW, aabbC, supTW, supTC,
                                               sortedC, ccls, out_char_scores);
  nms_fixpoint<<<2, 1024, 0, stream>>>(supTW, sortedW, out_wkeep, supTC, sortedC, out_ckeep);
}

// Round 5
// 141.326 us; speedup vs baseline: 4.7609x; 1.6485x over previous
//
#include <hip/hip_runtime.h>
#include <stdint.h>

typedef unsigned long long u64;
typedef unsigned int u32;

#define N_PIX (512*512)
#define KW 512
#define KC 2048
#define CAPW 4096
#define CAPC 4096
#define NUM_CLS 68
#define WORD_THR 0.5f
#define CHAR_THR 0.25f
#define IOU_THR 0.3f
#define NBLK 128
#define BS 256
#define GSZ (NBLK*BS)

struct SelState {
  u64 prefix;
  u32 kRem;
  u32 counter;
  u32 hist[256];
};

__device__ __forceinline__ u64 word_key(const float* wfg, int i){
  float wf = wfg[i];
  float s = wf > WORD_THR ? wf : 0.0f;
  return (((u64)__float_as_uint(s)) << 32) | (u64)(0xFFFFFFFFu - (u32)i);
}
__device__ __forceinline__ u64 char_key(const float* wfg, const float* cfg, int i){
  float wf = wfg[i]; float cf = cfg[i];
  float s = (wf > WORD_THR && cf > CHAR_THR) ? cf : 0.0f;
  return (((u64)__float_as_uint(s)) << 32) | (u64)(0xFFFFFFFFu - (u32)i);
}

// 16-byte aligned: sm.chunk is read via ulonglong2 (ds_read_b128 needs 16B alignment)
union alignas(16) Shm {
  struct { u32 hW[256]; u32 hC[256]; } h;
  u64 chunk[256];
  struct { u64 kw[32]; int changed; } n;
};

__global__ void init_state(SelState* stW, SelState* stC, u32* bars){
  int t = threadIdx.x;
  if (t==0){ stW->prefix=0ull; stW->kRem=KW; stW->counter=0u; }
  if (t==1){ stC->prefix=0ull; stC->kRem=KC; stC->counter=0u; }
  if (t < 8) bars[t] = 0u;
  for (int b=t; b<256; b+=BS){ stW->hist[b]=0u; stC->hist[b]=0u; }
}

// 64-lane parallel radix-scan of one 256-bin histogram (descending select)
__device__ __forceinline__ void scan_wave(SelState* st, int shift, int lane){
  u32 h[4];
  #pragma unroll
  for (int q=0;q<4;q++) h[q] = st->hist[lane*4+q];
  u32 lsum = h[0]+h[1]+h[2]+h[3];
  u32 v = lsum;
  #pragma unroll
  for (int off=1; off<64; off<<=1){
    u32 t2 = __shfl_down(v, off, 64);
    if (lane + off < 64) v += t2;
  }
  u32 above = v - lsum;                 // sum over lanes > lane
  u32 k = st->kRem;
  u32 sfx1 = h[3]+h[2]+h[1], sfx2 = h[3]+h[2], sfx3 = h[3];
  int best = -1;
  if      (above + sfx3 >= k) best = lane*4+3;
  else if (above + sfx2 >= k) best = lane*4+2;
  else if (above + sfx1 >= k) best = lane*4+1;
  else if (above + lsum >= k) best = lane*4+0;
  u64 m = __ballot(best >= 0);
  int hi_lane = 63 - __clzll(m);
  int d = __shfl(best, hi_lane, 64);
  u32 fd1_local = 0;
  if (lane == hi_lane){
    int q = d & 3;
    fd1_local = above + (q==3 ? 0u : (q==2 ? sfx3 : (q==1 ? sfx2 : sfx1)));
  }
  u32 fd1 = __shfl(fd1_local, hi_lane, 64);
  if (lane==0){
    st->prefix |= ((u64)(u32)d) << shift;
    st->kRem = k - fd1;
  }
  #pragma unroll
  for (int q=0;q<4;q++) st->hist[lane*4+q] = 0u;   // ready for next round
}

template<int W>
__device__ __forceinline__ void sup_row(int j, int lane, const float4* __restrict__ aabb,
                                        u64* __restrict__ supT, u32* __restrict__ rm){
  float4 bj = aabb[j];
  float aj = fmaxf(bj.z-bj.x,0.0f)*fmaxf(bj.w-bj.y,0.0f);
  u32 m = 0;
  #pragma unroll 4
  for (int w=0; w<W; w++){
    int i = w*64 + lane;
    float4 bi = aabb[i];
    float ai = fmaxf(bi.z-bi.x,0.0f)*fmaxf(bi.w-bi.y,0.0f);
    float ix1=fmaxf(bi.x,bj.x), iy1=fmaxf(bi.y,bj.y);
    float ix2=fminf(bi.z,bj.z), iy2=fminf(bi.w,bj.w);
    float inter = fmaxf(ix2-ix1,0.0f)*fmaxf(iy2-iy1,0.0f);
    float iou = inter/(ai+aj-inter+1e-6f);
    bool bit = (iou > IOU_THR) && (i < j);
    u64 b = __ballot(bit);
    if (b){ if (lane==0) supT[(size_t)j*W + w] = b; m |= 1u << w; }
  }
  if (lane==0) rm[j] = m;
}

template<int K, int W>
__device__ void nms_body(Shm& sm, const u64* __restrict__ supT, const u32* __restrict__ rm,
                         const u64* __restrict__ sorted, float* __restrict__ keep){
  int tid = threadIdx.x;
  int lane = tid & 63, wv = tid >> 6;
  constexpr int NB = K/BS;
  if (tid < W) sm.n.kw[tid] = ~0ull;
  __syncthreads();
  for(;;){
    if (tid==0) sm.n.changed = 0;
    __syncthreads();
    bool nb[NB];
    #pragma unroll
    for (int q=0;q<NB;q++){
      int j = q*BS + tid;
      u32 m = rm[j];
      u64 su = 0ull;
      while (m){ int w = __ffs(m)-1; m &= m-1u; su |= supT[(size_t)j*W + w] & sm.n.kw[w]; }
      nb[q] = (su == 0ull);
    }
    __syncthreads();
    #pragma unroll
    for (int q=0;q<NB;q++){
      u64 b = __ballot(nb[q]);
      if (lane==0){
        int wi = q*(BS/64) + wv;
        if (b != sm.n.kw[wi]){ sm.n.kw[wi] = b; sm.n.changed = 1; }
      }
    }
    __syncthreads();
    int ch = sm.n.changed;
    __syncthreads();
    if (!ch) break;
  }
  #pragma unroll
  for (int q=0;q<NB;q++){
    int j = q*BS + tid;
    u64 key = sorted[j];
    bool pos = ((u32)(key>>32)) != 0u;
    bool kp = (((sm.n.kw[j>>6] >> (j&63)) & 1ull) != 0ull) && pos;
    keep[j] = kp ? 1.0f : 0.0f;
  }
}

__global__ __launch_bounds__(BS)
void mega(const float* __restrict__ wfg, const float* __restrict__ cfg,
          const float* __restrict__ wtblr, const float* __restrict__ worient,
          const float* __restrict__ ctblr, const float* __restrict__ ccls,
          const int* p_sw, const int* p_sh, const int* p_ow, const int* p_oh,
          char* ws, float* out)
{
  // ws layout (phase-overlayed; all accesses < 631824 B)
  u64* candW   = (u64*)(ws + 0);        // dies after P6; then supTW
  u64* candC   = (u64*)(ws + 32768);    // dies after P6; then supTC
  u64* supTW   = (u64*)(ws + 0);
  u64* supTC   = (u64*)(ws + 32768);    // spans to 557056
  u32* ranks   = (u32*)(ws + 65536);    // [CAPW+CAPC]; dies after P6 (under supTC span)
  u64* sortedW = (u64*)(ws + 557056);
  u64* sortedC = (u64*)(ws + 561152);
  float4* aabbW= (float4*)(ws + 577536);
  float4* aabbC= (float4*)(ws + 585728);
  u32* rmW     = (u32*)(ws + 618496);
  u32* rmC     = (u32*)(ws + 620544);
  SelState* stW= (SelState*)(ws + 628736);
  u32* bars    = (u32*)(ws + 630016);   // 8 counters
  SelState* stC= (SelState*)(ws + 630784);

  float* out_cb = out;                          // char bboxes 2048*9
  float* out_cs = out + KC*9;                   // char scores 2048*68
  float* out_wb = out + KC*9 + KC*NUM_CLS;      // word bboxes 512*9
  float* out_wk = out_wb + KW*9;                // wkeep 512
  float* out_ck = out_wk + KW;                  // ckeep 2048

  __shared__ Shm sm;
  const int tid = threadIdx.x;
  const int gtid = blockIdx.x*BS + tid;
  const int lane = tid & 63;

  #define GBAR(i) do { __syncthreads(); if (tid==0){                                            \
      __hip_atomic_fetch_add(&bars[i], 1u, __ATOMIC_ACQ_REL, __HIP_MEMORY_SCOPE_AGENT);         \
      while (__hip_atomic_load(&bars[i], __ATOMIC_ACQUIRE, __HIP_MEMORY_SCOPE_AGENT) < (u32)NBLK) \
        __builtin_amdgcn_s_sleep(1);                                                            \
    } __syncthreads(); } while(0)

  // ---------- P0: zero ranks + histogram round 1 (top byte) ----------
  for (int t = gtid; t < CAPW+CAPC; t += GSZ) ranks[t] = 0u;
  for (int b=tid;b<256;b+=BS){ sm.h.hW[b]=0u; sm.h.hC[b]=0u; }
  __syncthreads();
  for (int i = gtid; i < N_PIX; i += GSZ){
    u64 kW = word_key(wfg,i);
    atomicAdd(&sm.h.hW[(u32)(kW>>56)&255u],1u);
    u64 kC = char_key(wfg,cfg,i);
    atomicAdd(&sm.h.hC[(u32)(kC>>56)&255u],1u);
  }
  __syncthreads();
  for (int b=tid;b<256;b+=BS){
    if (sm.h.hW[b]) atomicAdd(&stW->hist[b],sm.h.hW[b]);
    if (sm.h.hC[b]) atomicAdd(&stC->hist[b],sm.h.hC[b]);
  }
  GBAR(0);
  // ---------- P1: scan round 1 (block 0, waves 0/1) ----------
  if (blockIdx.x==0 && tid < 128){
    scan_wave(tid < 64 ? stW : stC, 56, lane);
  }
  GBAR(1);
  // ---------- P2: histogram round 2 (byte at 48, within prefix class) ----------
  {
    for (int b=tid;b<256;b+=BS){ sm.h.hW[b]=0u; sm.h.hC[b]=0u; }
    __syncthreads();
    u64 prefW = stW->prefix, prefC = stC->prefix;
    for (int i = gtid; i < N_PIX; i += GSZ){
      u64 kW = word_key(wfg,i);
      if ((kW>>56) == (prefW>>56)) atomicAdd(&sm.h.hW[(u32)(kW>>48)&255u],1u);
      u64 kC = char_key(wfg,cfg,i);
      if ((kC>>56) == (prefC>>56)) atomicAdd(&sm.h.hC[(u32)(kC>>48)&255u],1u);
    }
    __syncthreads();
    for (int b=tid;b<256;b+=BS){
      if (sm.h.hW[b]) atomicAdd(&stW->hist[b],sm.h.hW[b]);
      if (sm.h.hC[b]) atomicAdd(&stC->hist[b],sm.h.hC[b]);
    }
  }
  GBAR(2);
  // ---------- P3: scan round 2 ----------
  if (blockIdx.x==0 && tid < 128){
    scan_wave(tid < 64 ? stW : stC, 48, lane);
  }
  GBAR(3);
  // ---------- P4: compact (key >= 16-bit prefix threshold) ----------
  {
    u64 tW = stW->prefix, tC = stC->prefix;
    for (int i = gtid; i < N_PIX; i += GSZ){
      u64 kW = word_key(wfg,i);
      if (kW >= tW){ u32 p = atomicAdd(&stW->counter,1u); if (p < CAPW) candW[p]=kW; }
      u64 kC = char_key(wfg,cfg,i);
      if (kC >= tC){ u32 p = atomicAdd(&stC->counter,1u); if (p < CAPC) candC[p]=kC; }
    }
  }
  GBAR(4);
  // ---------- P5: tiled all-pairs rank count ----------
  {
    u32 CW = stW->counter; if (CW > CAPW) CW = CAPW;
    u32 CC = stC->counter; if (CC > CAPC) CC = CAPC;
    int nW = (int)((CW + 255) >> 8), nC = (int)((CC + 255) >> 8);
    int tilesW = nW*nW, tiles = tilesW + nC*nC;
    for (int t = blockIdx.x; t < tiles; t += NBLK){
      bool isW = (t < tilesW);
      int tt = isW ? t : t - tilesW;
      int n  = isW ? nW : nC;
      u32 C  = isW ? CW : CC;
      const u64* cand = isW ? candW : candC;
      u32* rk = isW ? ranks : (ranks + CAPW);
      int sg = tt / n, ch = tt - sg*n;
      __syncthreads();                      // LDS reuse guard
      int ci = ch*256 + tid;
      sm.chunk[tid] = (ci < (int)C) ? cand[ci] : 0ull;
      __syncthreads();
      int slot = sg*256 + tid;
      if (slot < (int)C){
        u64 my = cand[slot];
        int cnt = 0;
        const ulonglong2* cp = (const ulonglong2*)sm.chunk;
        #pragma unroll 8
        for (int i=0;i<128;i++){ ulonglong2 v = cp[i]; cnt += (v.x > my) + (v.y > my); }
        if (cnt) atomicAdd(&rk[slot], (u32)cnt);
      }
    }
  }
  GBAR(5);
  // ---------- P6: scatter to sorted order + box construction ----------
  {
    u32 CW = stW->counter; if (CW > CAPW) CW = CAPW;
    u32 CC = stC->counter; if (CC > CAPC) CC = CAPC;
    float swf = (float)(*p_sw) * 4.0f;    // WORD_STRIDE == CHAR_STRIDE == 4
    float shf = (float)(*p_sh) * 4.0f;
    float owm = (float)(*p_ow) - 1.0f, ohm = (float)(*p_oh) - 1.0f;
    for (int t = gtid; t < CAPW+CAPC; t += GSZ){
      bool isW = (t < CAPW);
      int slot = isW ? t : t - CAPW;
      u32 C = isW ? CW : CC;
      if (slot >= (int)C) continue;
      int rank = (int)ranks[t];
      int K = isW ? KW : KC;
      if (rank >= K) continue;
      u64 my = (isW ? candW : candC)[slot];
      (isW ? sortedW : sortedC)[rank] = my;
      u32 idx = 0xFFFFFFFFu - (u32)(my & 0xFFFFFFFFull);
      float score = __uint_as_float((u32)(my>>32));
      const float* tblr = isW ? wtblr : ctblr;
      float tt2 = tblr[idx], bb = tblr[N_PIX+idx], ll = tblr[2*N_PIX+idx], rr = tblr[3*N_PIX+idx];
      float xf = (float)(idx & 511u), yf = (float)(idx >> 9);
      float c = 1.0f, sn = 0.0f;
      if (isW){ float o = worient[idx]; c = cosf(o); sn = sinf(o); }
      float x1 = swf*(xf - ll), x2 = swf*(xf + rr);
      float y1 = shf*(yf - tt2), y2 = shf*(yf + bb);
      float ax = swf*xf, ay = shf*yf;
      float cx[4] = {x1,x2,x2,x1};
      float cy[4] = {y1,y1,y2,y2};
      float rx[4], ry[4];
      #pragma unroll
      for (int q=0;q<4;q++){
        float dx = cx[q]-ax, dy = cy[q]-ay;
        rx[q] = ax + dx*c - dy*sn;
        ry[q] = ay + dx*sn + dy*c;
      }
      float minx = fminf(fminf(rx[0],rx[1]),fminf(rx[2],rx[3]));
      float maxx = fmaxf(fmaxf(rx[0],rx[1]),fmaxf(rx[2],rx[3]));
      float miny = fminf(fminf(ry[0],ry[1]),fminf(ry[2],ry[3]));
      float maxy = fmaxf(fmaxf(ry[0],ry[1]),fmaxf(ry[2],ry[3]));
      (isW ? aabbW : aabbC)[rank] = make_float4(minx,miny,maxx,maxy);
      float* ob = isW ? out_wb : out_cb;
      #pragma unroll
      for (int q=0;q<4;q++){
        ob[rank*9 + 2*q]   = fminf(fmaxf(rintf(rx[q]),0.0f), owm);
        ob[rank*9 + 2*q+1] = fminf(fmaxf(rintf(ry[q]),0.0f), ohm);
      }
      ob[rank*9+8] = score;
    }
  }
  GBAR(6);
  // ---------- P7: suppression matrix (transposed, sparse rowmask) + class gather ----------
  {
    int gw = gtid >> 6;                    // 512 waves
    for (int row = gw; row < KW+KC; row += GSZ/64){
      if (row < KW) sup_row<KW/64>(row, lane, aabbW, supTW, rmW);
      else          sup_row<KC/64>(row-KW, lane, aabbC, supTC, rmC);
    }
    for (int t = gtid; t < KC*NUM_CLS; t += GSZ){
      int k = t / NUM_CLS;
      int c = t - k*NUM_CLS;
      u32 idx = 0xFFFFFFFFu - (u32)(sortedC[k] & 0xFFFFFFFFull);
      out_cs[t] = ccls[(size_t)c*N_PIX + idx];
    }
  }
  // ---------- P8: NMS Jacobi fixpoint (blocks 0,1; others arrive & exit) ----------
  __syncthreads();
  if (tid==0) __hip_atomic_fetch_add(&bars[7], 1u, __ATOMIC_ACQ_REL, __HIP_MEMORY_SCOPE_AGENT);
  if (blockIdx.x >= 2) return;
  if (tid==0){
    while (__hip_atomic_load(&bars[7], __ATOMIC_ACQUIRE, __HIP_MEMORY_SCOPE_AGENT) < (u32)NBLK)
      __builtin_amdgcn_s_sleep(1);
  }
  __syncthreads();
  if (blockIdx.x == 0) nms_body<KW, KW/64>(sm, supTW, rmW, sortedW, out_wk);
  else                 nms_body<KC, KC/64>(sm, supTC, rmC, sortedC, out_ck);
  #undef GBAR
}

extern "C" void kernel_launch(void* const* d_in, const int* in_sizes, int n_in,
                              void* d_out, int out_size, void* d_ws, size_t ws_size,
                              hipStream_t stream) {
  const float* wfg     = (const float*)d_in[0];
  const float* wtblr   = (const float*)d_in[1];
  const float* worient = (const float*)d_in[2];
  const float* cfg     = (const float*)d_in[3];
  const float* ctblr   = (const float*)d_in[4];
  const float* ccls    = (const float*)d_in[5];
  const int* p_sw = (const int*)d_in[6];
  const int* p_sh = (const int*)d_in[7];
  const int* p_ow = (const int*)d_in[8];
  const int* p_oh = (const int*)d_in[9];

  char* ws = (char*)d_ws;
  SelState* stW = (SelState*)(ws + 628736);
  u32* bars     = (u32*)(ws + 630016);
  SelState* stC = (SelState*)(ws + 630784);

  init_state<<<1, BS, 0, stream>>>(stW, stC, bars);
  mega<<<NBLK, BS, 0, stream>>>(wfg, cfg, wtblr, worient, ctblr, ccls,
                                p_sw, p_sh, p_ow, p_oh, ws, (float*)d_out);
}